// Round 11
// baseline (4885.692 us; speedup 1.0000x reference)
//
#include <hip/hip_runtime.h>

#define T_STEPS 4096
#define BATCH   128
#define HID     256

// Whole-time-loop inline asm. Rationale (rounds 2-9): hipcc's RA homes large
// loop-invariant register sets in AGPRs unconditionally; VALU cannot source
// AGPRs (round-7 assembler fact), so every GEMV fmac pays a v_accvgpr_read.
// With the ENTIRE 4096-step loop inside one asm block, weights live in
// hard-clobbered arch VGPRs v40-v103 for the whole kernel -- zero move tax.
// Round-10 asm fixes: divergent masks via v_cmp->vcc (not "s" operands),
// wave-uniform branch flag via v_readfirstlane, ds_write_b128 operands
// 64-bit aligned (v[36:39]).
__global__ __launch_bounds__(1024, 4)
void odenet_kernel(const float* __restrict__ x,
                   const float* __restrict__ W1, const float* __restrict__ b1,
                   const float* __restrict__ W2, const float* __restrict__ b2,
                   const float* __restrict__ W3, const float* __restrict__ b3,
                   float* __restrict__ out)
{
    const int b = blockIdx.x;    // batch element
    const int t = threadIdx.x;   // 0..1023
    const int w = t >> 6;        // wave 0..15: k-slice [16w,16w+16)
    const int l = t & 63;        // lane: columns 4l..4l+3
    const int k = 16 * w + (l & 15);

    __shared__ __align__(16) float x_lds[T_STEPS];   // 16 KB
    __shared__ __align__(16) float part[16][HID];    // 16 KB part[w][j]
    __shared__ __align__(16) float red[4];

    for (int i = t; i < T_STEPS; i += 1024) x_lds[i] = x[i * BATCH + b];

    const float w1a = W1[k];
    const float w1b = W1[HID + k];
    const float b1v = b1[k];
    const int   j   = t & 255;
    const float b2v = b2[j];
    const float w3v = W3[j];
    const float b3v = b3[0];

    // LDS byte offsets (low 32 bits of generic shared pointer = LDS offset)
    unsigned x_addr  = (unsigned)(uintptr_t)&x_lds[0];
    unsigned p_addr  = (unsigned)(uintptr_t)&part[w][4 * l];
    unsigned c_addr  = (unsigned)(uintptr_t)&part[0][j];
    unsigned r_addr  = (unsigned)(uintptr_t)&red[w & 3];
    unsigned rd_addr = (unsigned)(uintptr_t)&red[0];
    unsigned bp32    = (unsigned)((l ^ 32) << 2);        // ds_bpermute xor-32
    unsigned woff    = (unsigned)(w * 16384 + l * 16);   // W2 byte offset
    unsigned voff    = (unsigned)(b * 4);                // out byte offset
    unsigned emitf   = (t == 1023) ? 1u : 0u;            // per-lane store flag
    unsigned cw      = (w < 4) ? 1u : 0u;                // combine-wave flag
    unsigned long long l0m = 1ull;                       // lane-0 mask (uniform)

    float y = 0.0f;
    __syncthreads();

    asm volatile(
        // ---- load W2 slice into v40-v103 (16 x dwordx4, row stride 1KB) ----
        "s_mov_b32 s84, 0x1000\n\t"
        "global_load_dwordx4 v[40:43], %[wo], %[w2]\n\t"
        "v_add_u32 %[wo], 0x400, %[wo]\n\t"
        "global_load_dwordx4 v[44:47], %[wo], %[w2]\n\t"
        "v_add_u32 %[wo], 0x400, %[wo]\n\t"
        "global_load_dwordx4 v[48:51], %[wo], %[w2]\n\t"
        "v_add_u32 %[wo], 0x400, %[wo]\n\t"
        "global_load_dwordx4 v[52:55], %[wo], %[w2]\n\t"
        "v_add_u32 %[wo], 0x400, %[wo]\n\t"
        "global_load_dwordx4 v[56:59], %[wo], %[w2]\n\t"
        "v_add_u32 %[wo], 0x400, %[wo]\n\t"
        "global_load_dwordx4 v[60:63], %[wo], %[w2]\n\t"
        "v_add_u32 %[wo], 0x400, %[wo]\n\t"
        "global_load_dwordx4 v[64:67], %[wo], %[w2]\n\t"
        "v_add_u32 %[wo], 0x400, %[wo]\n\t"
        "global_load_dwordx4 v[68:71], %[wo], %[w2]\n\t"
        "v_add_u32 %[wo], 0x400, %[wo]\n\t"
        "global_load_dwordx4 v[72:75], %[wo], %[w2]\n\t"
        "v_add_u32 %[wo], 0x400, %[wo]\n\t"
        "global_load_dwordx4 v[76:79], %[wo], %[w2]\n\t"
        "v_add_u32 %[wo], 0x400, %[wo]\n\t"
        "global_load_dwordx4 v[80:83], %[wo], %[w2]\n\t"
        "v_add_u32 %[wo], 0x400, %[wo]\n\t"
        "global_load_dwordx4 v[84:87], %[wo], %[w2]\n\t"
        "v_add_u32 %[wo], 0x400, %[wo]\n\t"
        "global_load_dwordx4 v[88:91], %[wo], %[w2]\n\t"
        "v_add_u32 %[wo], 0x400, %[wo]\n\t"
        "global_load_dwordx4 v[92:95], %[wo], %[w2]\n\t"
        "v_add_u32 %[wo], 0x400, %[wo]\n\t"
        "global_load_dwordx4 v[96:99], %[wo], %[w2]\n\t"
        "v_add_u32 %[wo], 0x400, %[wo]\n\t"
        "global_load_dwordx4 v[100:103], %[wo], %[w2]\n\t"
        "s_waitcnt vmcnt(0)\n\t"

        "Lloop_%=:\n\t"
        // ---- emit y_n from thread 1023 only (vcc mask from per-lane flag) --
        "v_cmp_eq_u32 vcc, 1, %[emf]\n\t"
        "s_and_saveexec_b64 s[80:81], vcc\n\t"
        "global_store_dword %[vo], %[y], %[ob]\n\t"
        "s_mov_b64 exec, -1\n\t"
        "v_add_u32 %[vo], 0x200, %[vo]\n\t"
        // ---- layer 1: h = tanh(y*w1a + xt*w1b + b1) ----
        "ds_read_b32 v32, %[xa]\n\t"
        "v_add_u32 %[xa], 4, %[xa]\n\t"
        "v_mov_b32 v33, %[b1]\n\t"
        "s_waitcnt lgkmcnt(0)\n\t"
        "v_fmac_f32 v33, v32, %[w1b]\n\t"
        "v_fmac_f32 v33, %[y], %[w1a]\n\t"
        "v_mul_f32 v33, 0x4038aa3b, v33\n\t"   // z * 2*log2(e)
        "v_exp_f32 v33, v33\n\t"
        "s_nop 0\n\t"
        "v_add_f32 v33, 1.0, v33\n\t"
        "v_rcp_f32 v33, v33\n\t"
        "s_nop 0\n\t"
        "v_add_f32 v34, v33, v33\n\t"
        "v_sub_f32 v34, 1.0, v34\n\t"          // h in v34
        // ---- GEMV: 16 readlane broadcasts + 64 fmac (weights v40-v103) ----
        "v_mov_b32 v36, 0\n\t"
        "v_mov_b32 v37, 0\n\t"
        "v_mov_b32 v38, 0\n\t"
        "v_mov_b32 v39, 0\n\t"
        "v_readlane_b32 s80, v34, 0\n\t"
        "v_readlane_b32 s81, v34, 1\n\t"
        "v_readlane_b32 s82, v34, 2\n\t"
        "v_readlane_b32 s83, v34, 3\n\t"
        "v_fmac_f32 v36, s80, v40\n\t"
        "v_fmac_f32 v37, s80, v41\n\t"
        "v_fmac_f32 v38, s80, v42\n\t"
        "v_fmac_f32 v39, s80, v43\n\t"
        "v_readlane_b32 s80, v34, 4\n\t"
        "v_fmac_f32 v36, s81, v44\n\t"
        "v_fmac_f32 v37, s81, v45\n\t"
        "v_fmac_f32 v38, s81, v46\n\t"
        "v_fmac_f32 v39, s81, v47\n\t"
        "v_readlane_b32 s81, v34, 5\n\t"
        "v_fmac_f32 v36, s82, v48\n\t"
        "v_fmac_f32 v37, s82, v49\n\t"
        "v_fmac_f32 v38, s82, v50\n\t"
        "v_fmac_f32 v39, s82, v51\n\t"
        "v_readlane_b32 s82, v34, 6\n\t"
        "v_fmac_f32 v36, s83, v52\n\t"
        "v_fmac_f32 v37, s83, v53\n\t"
        "v_fmac_f32 v38, s83, v54\n\t"
        "v_fmac_f32 v39, s83, v55\n\t"
        "v_readlane_b32 s83, v34, 7\n\t"
        "v_fmac_f32 v36, s80, v56\n\t"
        "v_fmac_f32 v37, s80, v57\n\t"
        "v_fmac_f32 v38, s80, v58\n\t"
        "v_fmac_f32 v39, s80, v59\n\t"
        "v_readlane_b32 s80, v34, 8\n\t"
        "v_fmac_f32 v36, s81, v60\n\t"
        "v_fmac_f32 v37, s81, v61\n\t"
        "v_fmac_f32 v38, s81, v62\n\t"
        "v_fmac_f32 v39, s81, v63\n\t"
        "v_readlane_b32 s81, v34, 9\n\t"
        "v_fmac_f32 v36, s82, v64\n\t"
        "v_fmac_f32 v37, s82, v65\n\t"
        "v_fmac_f32 v38, s82, v66\n\t"
        "v_fmac_f32 v39, s82, v67\n\t"
        "v_readlane_b32 s82, v34, 10\n\t"
        "v_fmac_f32 v36, s83, v68\n\t"
        "v_fmac_f32 v37, s83, v69\n\t"
        "v_fmac_f32 v38, s83, v70\n\t"
        "v_fmac_f32 v39, s83, v71\n\t"
        "v_readlane_b32 s83, v34, 11\n\t"
        "v_fmac_f32 v36, s80, v72\n\t"
        "v_fmac_f32 v37, s80, v73\n\t"
        "v_fmac_f32 v38, s80, v74\n\t"
        "v_fmac_f32 v39, s80, v75\n\t"
        "v_readlane_b32 s80, v34, 12\n\t"
        "v_fmac_f32 v36, s81, v76\n\t"
        "v_fmac_f32 v37, s81, v77\n\t"
        "v_fmac_f32 v38, s81, v78\n\t"
        "v_fmac_f32 v39, s81, v79\n\t"
        "v_readlane_b32 s81, v34, 13\n\t"
        "v_fmac_f32 v36, s82, v80\n\t"
        "v_fmac_f32 v37, s82, v81\n\t"
        "v_fmac_f32 v38, s82, v82\n\t"
        "v_fmac_f32 v39, s82, v83\n\t"
        "v_readlane_b32 s82, v34, 14\n\t"
        "v_fmac_f32 v36, s83, v84\n\t"
        "v_fmac_f32 v37, s83, v85\n\t"
        "v_fmac_f32 v38, s83, v86\n\t"
        "v_fmac_f32 v39, s83, v87\n\t"
        "v_readlane_b32 s83, v34, 15\n\t"
        "v_fmac_f32 v36, s80, v88\n\t"
        "v_fmac_f32 v37, s80, v89\n\t"
        "v_fmac_f32 v38, s80, v90\n\t"
        "v_fmac_f32 v39, s80, v91\n\t"
        "v_fmac_f32 v36, s81, v92\n\t"
        "v_fmac_f32 v37, s81, v93\n\t"
        "v_fmac_f32 v38, s81, v94\n\t"
        "v_fmac_f32 v39, s81, v95\n\t"
        "v_fmac_f32 v36, s82, v96\n\t"
        "v_fmac_f32 v37, s82, v97\n\t"
        "v_fmac_f32 v38, s82, v98\n\t"
        "v_fmac_f32 v39, s82, v99\n\t"
        "v_fmac_f32 v36, s83, v100\n\t"
        "v_fmac_f32 v37, s83, v101\n\t"
        "v_fmac_f32 v38, s83, v102\n\t"
        "v_fmac_f32 v39, s83, v103\n\t"
        // ---- write partials, barrier ----
        "ds_write_b128 %[pa], v[36:39]\n\t"
        "s_waitcnt lgkmcnt(0)\n\t"
        "s_barrier\n\t"
        // ---- combine: waves 0-3 only (wave-uniform branch) ----
        "v_readfirstlane_b32 s85, %[cw]\n\t"
        "s_nop 0\n\t"
        "s_cmp_eq_u32 s85, 0\n\t"
        "s_cbranch_scc1 Lskip_%=\n\t"
        "ds_read_b32 v32, %[ca]\n\t"
        "ds_read_b32 v33, %[ca] offset:1024\n\t"
        "ds_read_b32 v34, %[ca] offset:2048\n\t"
        "ds_read_b32 v35, %[ca] offset:3072\n\t"
        "ds_read_b32 v36, %[ca] offset:4096\n\t"
        "ds_read_b32 v37, %[ca] offset:5120\n\t"
        "ds_read_b32 v38, %[ca] offset:6144\n\t"
        "ds_read_b32 v39, %[ca] offset:7168\n\t"
        "s_waitcnt lgkmcnt(0)\n\t"
        "v_add_f32 v32, v32, v33\n\t"
        "v_add_f32 v34, v34, v35\n\t"
        "v_add_f32 v36, v36, v37\n\t"
        "v_add_f32 v38, v38, v39\n\t"
        "v_add_f32 v32, v32, v34\n\t"
        "v_add_f32 v36, v36, v38\n\t"
        "v_add_f32 v32, v32, v36\n\t"
        "ds_read_b32 v33, %[ca] offset:8192\n\t"
        "ds_read_b32 v34, %[ca] offset:9216\n\t"
        "ds_read_b32 v35, %[ca] offset:10240\n\t"
        "ds_read_b32 v36, %[ca] offset:11264\n\t"
        "ds_read_b32 v37, %[ca] offset:12288\n\t"
        "ds_read_b32 v38, %[ca] offset:13312\n\t"
        "ds_read_b32 v39, %[ca] offset:14336\n\t"
        "s_waitcnt lgkmcnt(0)\n\t"
        "v_add_f32 v33, v33, v34\n\t"
        "v_add_f32 v35, v35, v36\n\t"
        "v_add_f32 v37, v37, v38\n\t"
        "v_add_f32 v33, v33, v35\n\t"
        "v_add_f32 v33, v33, v37\n\t"
        "v_add_f32 v33, v33, v39\n\t"
        "v_add_f32 v32, v32, v33\n\t"
        "ds_read_b32 v34, %[ca] offset:15360\n\t"
        "s_waitcnt lgkmcnt(0)\n\t"
        "v_add_f32 v32, v32, v34\n\t"
        "v_add_f32 v32, %[b2], v32\n\t"
        "v_mul_f32 v32, 0x4038aa3b, v32\n\t"
        "v_exp_f32 v32, v32\n\t"
        "s_nop 0\n\t"
        "v_add_f32 v32, 1.0, v32\n\t"
        "v_rcp_f32 v32, v32\n\t"
        "s_nop 0\n\t"
        "v_add_f32 v32, v32, v32\n\t"
        "v_sub_f32 v32, 1.0, v32\n\t"        // h2
        "v_mul_f32 v32, %[w3], v32\n\t"      // p = h2*W3[j]
        // 64-lane butterfly: 5x ds_swizzle (xor 1,2,4,8,16) + bpermute(32)
        "ds_swizzle_b32 v33, v32 offset:0x041f\n\t"
        "s_waitcnt lgkmcnt(0)\n\t"
        "v_add_f32 v32, v32, v33\n\t"
        "ds_swizzle_b32 v33, v32 offset:0x081f\n\t"
        "s_waitcnt lgkmcnt(0)\n\t"
        "v_add_f32 v32, v32, v33\n\t"
        "ds_swizzle_b32 v33, v32 offset:0x101f\n\t"
        "s_waitcnt lgkmcnt(0)\n\t"
        "v_add_f32 v32, v32, v33\n\t"
        "ds_swizzle_b32 v33, v32 offset:0x201f\n\t"
        "s_waitcnt lgkmcnt(0)\n\t"
        "v_add_f32 v32, v32, v33\n\t"
        "ds_swizzle_b32 v33, v32 offset:0x401f\n\t"
        "s_waitcnt lgkmcnt(0)\n\t"
        "v_add_f32 v32, v32, v33\n\t"
        "ds_bpermute_b32 v33, %[bp], v32\n\t"
        "s_waitcnt lgkmcnt(0)\n\t"
        "v_add_f32 v32, v32, v33\n\t"
        // red[w] write from lane 0
        "s_and_saveexec_b64 s[82:83], %[l0]\n\t"
        "ds_write_b32 %[ra], v32\n\t"
        "s_mov_b64 exec, -1\n\t"
        "Lskip_%=:\n\t"
        "s_waitcnt lgkmcnt(0)\n\t"
        "s_barrier\n\t"
        // ---- y update (all threads, identical) ----
        "ds_read_b128 v[32:35], %[rd]\n\t"
        "s_waitcnt lgkmcnt(0)\n\t"
        "v_add_f32 v32, v32, v33\n\t"
        "v_add_f32 v34, v34, v35\n\t"
        "v_add_f32 v32, v32, v34\n\t"
        "v_add_f32 v32, %[b3], v32\n\t"
        "v_add_f32 %[y], %[y], v32\n\t"
        // ---- loop control ----
        "s_sub_u32 s84, s84, 1\n\t"
        "s_cmp_lg_u32 s84, 0\n\t"
        "s_cbranch_scc1 Lloop_%=\n\t"
        : [y]"+v"(y), [xa]"+v"(x_addr), [vo]"+v"(voff), [wo]"+v"(woff)
        : [w2]"s"(W2), [ob]"s"(out), [l0]"s"(l0m),
          [emf]"v"(emitf), [cw]"v"(cw),
          [pa]"v"(p_addr), [ca]"v"(c_addr), [ra]"v"(r_addr), [rd]"v"(rd_addr),
          [bp]"v"(bp32), [w1a]"v"(w1a), [w1b]"v"(w1b), [b1]"v"(b1v),
          [b2]"v"(b2v), [w3]"v"(w3v), [b3]"v"(b3v)
        : "memory", "scc", "vcc",
          "s80","s81","s82","s83","s84","s85",
          "v32","v33","v34","v35","v36","v37","v38","v39",
          "v40","v41","v42","v43","v44","v45","v46","v47",
          "v48","v49","v50","v51","v52","v53","v54","v55",
          "v56","v57","v58","v59","v60","v61","v62","v63",
          "v64","v65","v66","v67","v68","v69","v70","v71",
          "v72","v73","v74","v75","v76","v77","v78","v79",
          "v80","v81","v82","v83","v84","v85","v86","v87",
          "v88","v89","v90","v91","v92","v93","v94","v95",
          "v96","v97","v98","v99","v100","v101","v102","v103");
}

extern "C" void kernel_launch(void* const* d_in, const int* in_sizes, int n_in,
                              void* d_out, int out_size, void* d_ws, size_t ws_size,
                              hipStream_t stream) {
    const float* x  = (const float*)d_in[0];
    const float* W1 = (const float*)d_in[1];
    const float* b1 = (const float*)d_in[2];
    const float* W2 = (const float*)d_in[3];
    const float* b2 = (const float*)d_in[4];
    const float* W3 = (const float*)d_in[5];
    const float* b3 = (const float*)d_in[6];
    float* out = (float*)d_out;

    odenet_kernel<<<dim3(BATCH), dim3(1024), 0, stream>>>(x, W1, b1, W2, b2, W3, b3, out);
}

// Round 15
// 3468.317 us; speedup vs baseline: 1.4087x; 1.4087x over previous
//
#include <hip/hip_runtime.h>

#define T_STEPS 4096
#define BATCH   128
#define HID     256

typedef float f2 __attribute__((ext_vector_type(2)));
typedef float f4 __attribute__((ext_vector_type(4)));

__device__ __forceinline__ float fast_tanh(float z) {
    // tanh(z) = 1 - 2/(exp(2z)+1); exact saturation, ~1e-6 abs err
    float e = __expf(2.0f * z);
    return 1.0f - 2.0f / (e + 1.0f);
}

__device__ __forceinline__ float rlane(float v, int l) {
    return __uint_as_float(__builtin_amdgcn_readlane(__float_as_uint(v), l));
}

// one level of the canonical GCN wave64 DPP reduction (VALU pipe)
template <int CTRL, int ROW_MASK>
__device__ __forceinline__ float dpp_add(float x) {
    int s = __builtin_amdgcn_update_dpp(0, __float_as_int(x), CTRL, ROW_MASK, 0xf, false);
    return x + __int_as_float(s);
}

#define RPT16(M) M(0) M(1) M(2) M(3) M(4) M(5) M(6) M(7) \
                 M(8) M(9) M(10) M(11) M(12) M(13) M(14) M(15)

// 1024 threads = 16 waves (4/SIMD). Wave w owns k-slice [16w,16w+16);
// lane l owns columns 4l..4l+3. This is the round-9 kernel (3491us, passed)
// with ONE change: the GEMV uses float2 ext-vectors so clang emits
// v_pk_fma_f32 (2 MACs/instr) -- 64 fmac/wave -> 32 pk_fma/wave, saving
// ~256 cyc/step of SIMD issue. Accumulator pairing (acc01=chains 0,1;
// acc23=chains 2,3) preserves the exact original summation order ->
// bit-identical output. Whole-loop asm abandoned: 1 pass (4886us, worse
// than HIP) + 4 unexplained failures across 5 rounds.
__global__ __launch_bounds__(1024, 4)
void odenet_kernel(const float* __restrict__ x,
                   const float* __restrict__ W1, const float* __restrict__ b1,
                   const float* __restrict__ W2, const float* __restrict__ b2,
                   const float* __restrict__ W3, const float* __restrict__ b3,
                   float* __restrict__ out)
{
    const int b = blockIdx.x;    // batch element
    const int t = threadIdx.x;   // 0..1023
    const int w = t >> 6;        // wave 0..15: k-slice [16w,16w+16)
    const int l = t & 63;        // lane: columns 4l..4l+3
    const int k = 16 * w + (l & 15);   // this lane's h1 index (x4 redundant)

    __shared__ float x_lds[T_STEPS];       // 16 KB
    __shared__ float part[16][HID];        // 16 KB  part[w][j]
    __shared__ __align__(16) float red[4]; // per-combine-wave y-dot partials

    for (int i = t; i < T_STEPS; i += 1024) x_lds[i] = x[i * BATCH + b];

    // ---- W2 slice: rows 16w..16w+15, cols 4l..4l+3, as float2 pairs ----
    #define DECLQ(i) \
        f2 wa##i = *(const f2*)(W2 + (16*w + (i)) * HID + 4*l); \
        f2 wb##i = *(const f2*)(W2 + (16*w + (i)) * HID + 4*l + 2);
    RPT16(DECLQ)

    // ---- layer-1 params for this lane's k ----
    const float w1a = W1[k];
    const float w1b = W1[HID + k];
    const float b1v = b1[k];

    // ---- combine params (threads 0..255, col j = t) ----
    const float b2v = (t < 256) ? b2[t] : 0.f;
    const float w3v = (t < 256) ? W3[t] : 0.f;
    const float b3v = b3[0];

    float y = 0.0f;
    __syncthreads();

    #pragma unroll 1
    for (int n = 0; n < T_STEPS; ++n) {
        // per-iteration pin: keeps the weight live-range anchored (round 9)
        #define PINQ(i) asm volatile("" : "+v"(wa##i), "+v"(wb##i));
        RPT16(PINQ)

        if (t == 1023) out[n * BATCH + b] = y;   // emit y_n (pre-update)

        // ---- layer 1, in-wave (no barrier) ----
        const float xt = x_lds[n];
        const float h  = fast_tanh(fmaf(y, w1a, fmaf(xt, w1b, b1v)));

        // ---- GEMV: 16 readlane broadcasts + 32 v_pk_fma_f32 ----
        f2 acc01 = {0.f, 0.f};
        f2 acc23 = {0.f, 0.f};
        #define STEPK(i) { \
            const float s = rlane(h, i); \
            f2 sv; sv.x = s; sv.y = s; \
            acc01 += sv * wa##i; \
            acc23 += sv * wb##i; }
        RPT16(STEPK)

        f4 acc; acc.x = acc01.x; acc.y = acc01.y; acc.z = acc23.x; acc.w = acc23.y;
        *(f4*)(&part[w][4 * l]) = acc;     // coalesced ds_write_b128
        __syncthreads();                   // B1: partials ready

        // ---- combine (threads 0..255): col sums, tanh, w3-dot, DPP reduce ----
        if (t < 256) {
            float s0 = 0.f, s1 = 0.f, s2 = 0.f, s3 = 0.f;
            #pragma unroll
            for (int p = 0; p < 4; ++p) {
                s0 += part[4*p + 0][t];
                s1 += part[4*p + 1][t];
                s2 += part[4*p + 2][t];
                s3 += part[4*p + 3][t];
            }
            float h2 = fast_tanh(((s0 + s1) + (s2 + s3)) + b2v);
            float p  = h2 * w3v;
            // canonical wave64 DPP reduce: total lands in lane 63
            p = dpp_add<0x111, 0xf>(p);   // row_shr:1
            p = dpp_add<0x112, 0xf>(p);   // row_shr:2
            p = dpp_add<0x114, 0xf>(p);   // row_shr:4
            p = dpp_add<0x118, 0xf>(p);   // row_shr:8
            p = dpp_add<0x142, 0xa>(p);   // row_bcast:15 (rows 1,3)
            p = dpp_add<0x143, 0xc>(p);   // row_bcast:31 (rows 2,3)
            if (l == 63) red[w] = p;      // combine waves w = 0..3
        }
        __syncthreads();                   // B2: red ready

        // all threads update y identically
        f4 r = *(const f4*)red;            // uniform ds_read_b128
        y += ((r.x + r.y) + (r.z + r.w)) + b3v;
    }
}

extern "C" void kernel_launch(void* const* d_in, const int* in_sizes, int n_in,
                              void* d_out, int out_size, void* d_ws, size_t ws_size,
                              hipStream_t stream) {
    const float* x  = (const float*)d_in[0];
    const float* W1 = (const float*)d_in[1];
    const float* b1 = (const float*)d_in[2];
    const float* W2 = (const float*)d_in[3];
    const float* b2 = (const float*)d_in[4];
    const float* W3 = (const float*)d_in[5];
    const float* b3 = (const float*)d_in[6];
    float* out = (float*)d_out;

    odenet_kernel<<<dim3(BATCH), dim3(1024), 0, stream>>>(x, W1, b1, W2, b2, W3, b3, out);
}